// Round 3
// baseline (328.278 us; speedup 1.0000x reference)
//
#include <hip/hip_runtime.h>

#define KDIM 1024

typedef _Float16 half8 __attribute__((ext_vector_type(8)));
typedef _Float16 half4 __attribute__((ext_vector_type(4)));
typedef float f32x4 __attribute__((ext_vector_type(4)));

#if defined(__has_builtin)
#if __has_builtin(__builtin_amdgcn_global_load_lds)
#define HAVE_GLDS 1
#endif
#endif

__device__ __forceinline__ void stage16(const _Float16* g, _Float16* wave_base, int lane) {
#ifdef HAVE_GLDS
  __builtin_amdgcn_global_load_lds(
      (const __attribute__((address_space(1))) void*)g,
      (__attribute__((address_space(3))) void*)wave_base, 16, 0, 0);
#else
  *(half8*)(wave_base + lane * 8) = *(const half8*)g;
#endif
}

// ---------------- cast x (f32 -> f16), 4 elems/thread ----------------
__global__ void cast_x_kernel(const float* __restrict__ x, _Float16* __restrict__ xb) {
  size_t i = ((size_t)blockIdx.x * 256 + threadIdx.x) * 4;
  float4 v = *(const float4*)(x + i);
  half4 h = { (_Float16)v.x, (_Float16)v.y, (_Float16)v.z, (_Float16)v.w };
  *(half4*)(xb + i) = h;
}

// ------- transpose-cast weights into packed Wqkvt[3][n][k]; Wq scaled by 1/8 ----
__global__ void wtrans_kernel(const float* __restrict__ Wq, const float* __restrict__ Wk,
                              const float* __restrict__ Wv, _Float16* __restrict__ Wqkvt) {
  int z = blockIdx.z;
  const float* src = z == 0 ? Wq : (z == 1 ? Wk : Wv);
  _Float16* dst = Wqkvt + (size_t)z * KDIM * KDIM;
  float sc = (z == 0) ? 0.125f : 1.0f;  // fold 1/sqrt(HD)=1/8 into Wq
  __shared__ _Float16 tile[32][33];
  int tx = threadIdx.x & 31, ty = threadIdx.x >> 5;
  int c0 = blockIdx.x * 32, r0 = blockIdx.y * 32;
#pragma unroll
  for (int i = 0; i < 4; i++) {
    int r = r0 + ty + i * 8;
    tile[tx][ty + i * 8] = (_Float16)(src[(size_t)r * KDIM + c0 + tx] * sc);
  }
  __syncthreads();
#pragma unroll
  for (int i = 0; i < 4; i++) {
    int n = c0 + ty + i * 8;
    dst[(size_t)n * KDIM + r0 + tx] = tile[ty + i * 8][tx];
  }
}

// ---------------- mask -> bitmask (1 bit per (b,q,t), t fastest) ----------------
__global__ void maskbits_kernel(const float* __restrict__ m, unsigned long long* __restrict__ bits) {
  size_t i = (size_t)blockIdx.x * 256 + threadIdx.x;
  unsigned long long b = __ballot(m[i] != 0.0f);
  if ((threadIdx.x & 63) == 0) bits[i >> 6] = b;
}

// ------------- fused QKV GEMM: C[M=8192][N=3072] = xb * Wqkvt^T -------------
// n<1024 -> Qt[b,h,d,s] (packed half4 stores), n<2048 -> Kh[b,h,s,d] (scalar),
// else -> Vth[b,h,d,s] (packed half4 stores).
__global__ __launch_bounds__(256, 2)
void gemm_kernel(const _Float16* __restrict__ A, const _Float16* __restrict__ Bt,
                 _Float16* __restrict__ Qt, _Float16* __restrict__ Kh,
                 _Float16* __restrict__ Vth) {
  __shared__ _Float16 As[128 * 32];
  __shared__ _Float16 Bs[128 * 32];
  int tid = threadIdx.x;
  int lane = tid & 63, w4 = tid >> 6;
  int la = lane & 15, qd = lane >> 4;
  int wm = w4 & 1, wn = w4 >> 1;
  int m0 = blockIdx.y * 128, n0 = blockIdx.x * 128;
  int r = tid >> 2, c = (tid & 3) * 8;
  const _Float16* Ag = A + (size_t)(m0 + r) * KDIM + c;
  const _Float16* Bg = Bt + (size_t)(n0 + r) * KDIM + c;
  _Float16* a0 = As + w4 * 512;
  _Float16* b0 = Bs + w4 * 512;
  f32x4 acc[4][4] = {};
  for (int kt = 0; kt < KDIM; kt += 32) {
    stage16(Ag + kt, a0, lane);
    stage16(Ag + (size_t)64 * KDIM + kt, a0 + 2048, lane);
    stage16(Bg + kt, b0, lane);
    stage16(Bg + (size_t)64 * KDIM + kt, b0 + 2048, lane);
    __syncthreads();
    half8 af[4], bf[4];
#pragma unroll
    for (int mi = 0; mi < 4; mi++)
      af[mi] = *(const half8*)(As + (wm * 64 + mi * 16 + la) * 32 + qd * 8);
#pragma unroll
    for (int ni = 0; ni < 4; ni++)
      bf[ni] = *(const half8*)(Bs + (wn * 64 + ni * 16 + la) * 32 + qd * 8);
#pragma unroll
    for (int mi = 0; mi < 4; mi++)
#pragma unroll
      for (int ni = 0; ni < 4; ni++)
        acc[mi][ni] = __builtin_amdgcn_mfma_f32_16x16x32_f16(af[mi], bf[ni], acc[mi][ni], 0, 0, 0);
    __syncthreads();
  }
  int which = n0 >> 10;                      // 0:Q 1:K 2:V (uniform per block)
  int hh = ((n0 + wn * 64) >> 6) & 15;       // uniform per wave
#pragma unroll
  for (int mi = 0; mi < 4; mi++)
#pragma unroll
    for (int ni = 0; ni < 4; ni++) {
      f32x4 v = acc[mi][ni];
      int mb = m0 + wm * 64 + mi * 16 + qd * 4;  // 4 consecutive m = rg
      int b = mb >> 10, s = mb & 1023;
      int d = ni * 16 + la;
      if (which == 1) {
#pragma unroll
        for (int rg = 0; rg < 4; rg++)
          Kh[(((size_t)(b * 16 + hh)) * 1024 + s + rg) * 64 + d] = (_Float16)v[rg];
      } else {
        _Float16* dst = (which == 0) ? Qt : Vth;
        half4 h = { (_Float16)v[0], (_Float16)v[1], (_Float16)v[2], (_Float16)v[3] };
        *(half4*)(dst + (((size_t)(b * 16 + hh)) * 64 + d) * 1024 + s) = h;
      }
    }
}

// ---------------- fused attention ----------------
// grid 2048 linear, XCD-swizzled so the 16 q-tiles of one (b,h) share an XCD.
// S^T = K*Q^T via 16x16x32 (C-layout == A-frag layout of 16x16x16),
// exp in-register, PV via 16x16x16 (no P LDS round-trip).
__global__ __launch_bounds__(256, 4)
void attn_kernel(const _Float16* __restrict__ Qt, const _Float16* __restrict__ K,
                 const _Float16* __restrict__ Vt, const unsigned long long* __restrict__ mbits,
                 float* __restrict__ out) {
  __shared__ _Float16 Ks[2 * 64 * 32];  // [ks=d/32][t][32]
  __shared__ _Float16 Vs[2 * 64 * 32];  // [th=t/32][d][32]
  int tid = threadIdx.x;
  int lane = tid & 63, w4 = tid >> 6;
  int la = lane & 15, qd = lane >> 4;
  // XCD swizzle: linear = ((hb/8)*16 + qt)*8 + hb%8  => same hb -> same (idx%8)
  int linear = blockIdx.x;
  int xlo = linear & 7;
  int tmp = linear >> 3;
  int qt = tmp & 15;
  int hb = (tmp >> 4) * 8 + xlo;
  int h = hb & 15, b = hb >> 4;
  const _Float16* Qp = Qt + ((size_t)(b * 16 + h)) * 64 * 1024;  // [d][s]
  const _Float16* Kp = K + ((size_t)(b * 16 + h)) * 1024 * 64;   // [s][d]
  const _Float16* Vp = Vt + ((size_t)(b * 16 + h)) * 64 * 1024;  // [d][s]
  int q0w = qt * 64 + w4 * 16;
  // Q B-frag (one-time scalar loads): qf[ks][j] = Q[q=q0w+la][d=ks*32+qd*8+j]
  half8 qf[2];
#pragma unroll
  for (int ks = 0; ks < 2; ks++)
#pragma unroll
    for (int j = 0; j < 8; j++)
      qf[ks][j] = Qp[(size_t)(ks * 32 + qd * 8 + j) * 1024 + q0w + la];
  f32x4 acco[4] = {};
  float rs = 0.0f;
  int r = tid >> 2, c = (tid & 3) * 8;
  _Float16* kbase = Ks + w4 * 512;
  _Float16* vbase = Vs + w4 * 512;
  const unsigned long long* mrow = mbits + (size_t)b * 1024 * 16;
  for (int tt = 0; tt < 16; tt++) {
    stage16(Kp + (size_t)(tt * 64 + r) * 64 + c, kbase, lane);
    stage16(Kp + (size_t)(tt * 64 + r) * 64 + 32 + c, kbase + 2048, lane);
    stage16(Vp + (size_t)r * 1024 + tt * 64 + c, vbase, lane);
    stage16(Vp + (size_t)r * 1024 + tt * 64 + 32 + c, vbase + 2048, lane);
    __syncthreads();
    // S^T tiles: D[t' = qd*4+rg][q = la], A = K-frag, B = Q-frag
    f32x4 accs[4] = {};
#pragma unroll
    for (int tsub = 0; tsub < 4; tsub++)
#pragma unroll
      for (int ks = 0; ks < 2; ks++) {
        half8 kf = *(const half8*)(Ks + ks * 2048 + (tsub * 16 + la) * 32 + qd * 8);
        accs[tsub] = __builtin_amdgcn_mfma_f32_16x16x32_f16(kf, qf[ks], accs[tsub], 0, 0, 0);
      }
    unsigned long long mw = mrow[(size_t)(q0w + la) * 16 + tt];
    // exp in-register; accs C-layout IS the A-frag layout for 16x16x16 (j = rg)
#pragma unroll
    for (int tsub = 0; tsub < 4; tsub++) {
      half4 pf;
#pragma unroll
      for (int rg = 0; rg < 4; rg++) {
        float e = ((mw >> (tsub * 16 + qd * 4 + rg)) & 1ull) ? __expf(accs[tsub][rg]) : 0.0f;
        rs += e;
        pf[rg] = (_Float16)e;
      }
#pragma unroll
      for (int nsub = 0; nsub < 4; nsub++) {
        half4 vf = *(const half4*)(Vs + (tsub >> 1) * 2048 + (nsub * 16 + la) * 32 +
                                   (tsub & 1) * 16 + qd * 4);
        acco[nsub] = __builtin_amdgcn_mfma_f32_16x16x16f16(pf, vf, acco[nsub], 0, 0, 0);
      }
    }
    __syncthreads();
  }
  // rs currently: lane (la,qd) holds partial sum for q=la over t in its qd quadrants
  rs += __shfl_xor(rs, 16);
  rs += __shfl_xor(rs, 32);
  float inv_q = 1.0f / (rs + 1e-8f);  // valid in all lanes; lane index == q for la
  float* op = out + (size_t)b * 1024 * 1024 + (size_t)h * 64;
#pragma unroll
  for (int rg = 0; rg < 4; rg++) {
    float inv = __shfl(inv_q, qd * 4 + rg);  // row q' = qd*4+rg lives at lane q'
    int s = q0w + qd * 4 + rg;
#pragma unroll
    for (int nsub = 0; nsub < 4; nsub++)
      op[(size_t)s * 1024 + nsub * 16 + la] = acco[nsub][rg] * inv;
  }
}

extern "C" void kernel_launch(void* const* d_in, const int* in_sizes, int n_in,
                              void* d_out, int out_size, void* d_ws, size_t ws_size,
                              hipStream_t stream) {
  (void)in_sizes; (void)n_in; (void)out_size; (void)ws_size;
  const float* x = (const float*)d_in[0];
  const float* am = (const float*)d_in[1];
  const float* Wq = (const float*)d_in[2];
  const float* Wk = (const float*)d_in[3];
  const float* Wv = (const float*)d_in[4];
  float* out = (float*)d_out;

  char* p = (char*)d_ws;
  _Float16* xb = (_Float16*)p;    p += (size_t)8192 * 1024 * 2;      // 16 MB
  _Float16* Wqkvt = (_Float16*)p; p += (size_t)3 * 1024 * 1024 * 2;  // 6 MB
  _Float16* Qt = (_Float16*)p;    p += (size_t)8192 * 1024 * 2;      // [b,h,d,s]
  _Float16* Kh = (_Float16*)p;    p += (size_t)8192 * 1024 * 2;      // [b,h,s,d]
  _Float16* Vth = (_Float16*)p;   p += (size_t)8192 * 1024 * 2;      // [b,h,d,s]
  unsigned long long* mb = (unsigned long long*)p;                   // 1 MB

  cast_x_kernel<<<8192, 256, 0, stream>>>(x, xb);
  wtrans_kernel<<<dim3(32, 32, 3), 256, 0, stream>>>(Wq, Wk, Wv, Wqkvt);
  maskbits_kernel<<<32768, 256, 0, stream>>>(am, mb);
  gemm_kernel<<<dim3(24, 64), 256, 0, stream>>>(xb, Wqkvt, Qt, Kh, Vth);
  attn_kernel<<<2048, 256, 0, stream>>>(Qt, Kh, Vth, mb, out);
}

// Round 4
// 260.767 us; speedup vs baseline: 1.2589x; 1.2589x over previous
//
#include <hip/hip_runtime.h>

#define KDIM 1024

typedef _Float16 half8 __attribute__((ext_vector_type(8)));
typedef _Float16 half4 __attribute__((ext_vector_type(4)));
typedef float f32x4 __attribute__((ext_vector_type(4)));

#if defined(__has_builtin)
#if __has_builtin(__builtin_amdgcn_global_load_lds)
#define HAVE_GLDS 1
#endif
#endif

__device__ __forceinline__ void stage16(const _Float16* g, _Float16* wave_base, int lane) {
#ifdef HAVE_GLDS
  __builtin_amdgcn_global_load_lds(
      (const __attribute__((address_space(1))) void*)g,
      (__attribute__((address_space(3))) void*)wave_base, 16, 0, 0);
#else
  *(half8*)(wave_base + lane * 8) = *(const half8*)g;
#endif
}

// ---------------- cast x (f32 -> f16), 4 elems/thread ----------------
__global__ void cast_x_kernel(const float* __restrict__ x, _Float16* __restrict__ xb) {
  size_t i = ((size_t)blockIdx.x * 256 + threadIdx.x) * 4;
  float4 v = *(const float4*)(x + i);
  half4 h = { (_Float16)v.x, (_Float16)v.y, (_Float16)v.z, (_Float16)v.w };
  *(half4*)(xb + i) = h;
}

// ------- transpose-cast weights into packed Wqkvt[3][n][k]; Wq scaled by 1/8 ----
__global__ void wtrans_kernel(const float* __restrict__ Wq, const float* __restrict__ Wk,
                              const float* __restrict__ Wv, _Float16* __restrict__ Wqkvt) {
  int z = blockIdx.z;
  const float* src = z == 0 ? Wq : (z == 1 ? Wk : Wv);
  _Float16* dst = Wqkvt + (size_t)z * KDIM * KDIM;
  float sc = (z == 0) ? 0.125f : 1.0f;
  __shared__ _Float16 tile[32][33];
  int tx = threadIdx.x & 31, ty = threadIdx.x >> 5;
  int c0 = blockIdx.x * 32, r0 = blockIdx.y * 32;
#pragma unroll
  for (int i = 0; i < 4; i++) {
    int r = r0 + ty + i * 8;
    tile[tx][ty + i * 8] = (_Float16)(src[(size_t)r * KDIM + c0 + tx] * sc);
  }
  __syncthreads();
#pragma unroll
  for (int i = 0; i < 4; i++) {
    int n = c0 + ty + i * 8;
    dst[(size_t)n * KDIM + r0 + tx] = tile[ty + i * 8][tx];
  }
}

// ---------------- mask -> bitmask (1 bit per (b,q,t), t fastest) ----------------
__global__ void maskbits_kernel(const float* __restrict__ m, unsigned long long* __restrict__ bits) {
  size_t i = (size_t)blockIdx.x * 256 + threadIdx.x;
  unsigned long long b = __ballot(m[i] != 0.0f);
  if ((threadIdx.x & 63) == 0) bits[i >> 6] = b;
}

// ------------- fused QKV GEMM: C[M=8192][N=3072] = xb * Wqkvt^T -------------
// Q -> Qt[b,h,d,s], K -> Kh[b,h,s,d], V -> Vth[b,h,d,s].
// Q/V epilogue: LDS-transpose per wave -> b128 coalesced stores.
__global__ __launch_bounds__(256, 2)
void gemm_kernel(const _Float16* __restrict__ A, const _Float16* __restrict__ Bt,
                 _Float16* __restrict__ Qt, _Float16* __restrict__ Kh,
                 _Float16* __restrict__ Vth) {
  __shared__ _Float16 As[128 * 32];
  __shared__ _Float16 Bs[128 * 32];
  int tid = threadIdx.x;
  int lane = tid & 63, w4 = tid >> 6;
  int la = lane & 15, qd = lane >> 4;
  int wm = w4 & 1, wn = w4 >> 1;
  int m0 = blockIdx.y * 128, n0 = blockIdx.x * 128;
  int r = tid >> 2, c = (tid & 3) * 8;
  const _Float16* Ag = A + (size_t)(m0 + r) * KDIM + c;
  const _Float16* Bg = Bt + (size_t)(n0 + r) * KDIM + c;
  _Float16* a0 = As + w4 * 512;
  _Float16* b0 = Bs + w4 * 512;
  f32x4 acc[4][4] = {};
  for (int kt = 0; kt < KDIM; kt += 32) {
    stage16(Ag + kt, a0, lane);
    stage16(Ag + (size_t)64 * KDIM + kt, a0 + 2048, lane);
    stage16(Bg + kt, b0, lane);
    stage16(Bg + (size_t)64 * KDIM + kt, b0 + 2048, lane);
    __syncthreads();
    half8 af[4], bf[4];
#pragma unroll
    for (int mi = 0; mi < 4; mi++)
      af[mi] = *(const half8*)(As + (wm * 64 + mi * 16 + la) * 32 + qd * 8);
#pragma unroll
    for (int ni = 0; ni < 4; ni++)
      bf[ni] = *(const half8*)(Bs + (wn * 64 + ni * 16 + la) * 32 + qd * 8);
#pragma unroll
    for (int mi = 0; mi < 4; mi++)
#pragma unroll
      for (int ni = 0; ni < 4; ni++)
        acc[mi][ni] = __builtin_amdgcn_mfma_f32_16x16x32_f16(af[mi], bf[ni], acc[mi][ni], 0, 0, 0);
    __syncthreads();
  }
  int which = n0 >> 10;                 // 0:Q 1:K 2:V (uniform per block)
  int hh = ((n0 + wn * 64) >> 6) & 15;  // uniform per wave
  int mbase = m0 + wm * 64;
  int b = mbase >> 10, s0 = mbase & 1023;
  if (which == 1) {
#pragma unroll
    for (int mi = 0; mi < 4; mi++)
#pragma unroll
      for (int ni = 0; ni < 4; ni++) {
        f32x4 v = acc[mi][ni];
        int s = s0 + mi * 16 + qd * 4;
        int d = ni * 16 + la;
#pragma unroll
        for (int rg = 0; rg < 4; rg++)
          Kh[(((size_t)(b * 16 + hh)) * 1024 + s + rg) * 64 + d] = (_Float16)v[rg];
      }
  } else {
    _Float16* dst = (which == 0) ? Qt : Vth;
    // wave-private transpose patch: 16 rows x 72 halves (144B stride: 16B-aligned,
    // bank-perfect for both the b64 writes and b128 reads)
    _Float16* ep = (w4 < 2) ? (As + w4 * 2048) : (Bs + (w4 - 2) * 2048);
    _Float16* base = dst + ((size_t)(b * 16 + hh)) * 64 * 1024;
    int rr = lane >> 2, c4 = lane & 3;
#pragma unroll
    for (int ni = 0; ni < 4; ni++) {
#pragma unroll
      for (int mi = 0; mi < 4; mi++) {
        f32x4 v = acc[mi][ni];
        half4 hv = { (_Float16)v[0], (_Float16)v[1], (_Float16)v[2], (_Float16)v[3] };
        *(half4*)(ep + la * 72 + mi * 16 + qd * 4) = hv;  // row=d(la), col=s
      }
      // same-wave DS ops are in-order: safe to read back without barrier
      half8 o0 = *(const half8*)(ep + rr * 72 + c4 * 16);
      half8 o1 = *(const half8*)(ep + rr * 72 + c4 * 16 + 8);
      _Float16* gp = base + (size_t)(ni * 16 + rr) * 1024 + s0 + c4 * 16;
      *(half8*)gp = o0;
      *(half8*)(gp + 8) = o1;
    }
  }
}

// ---------------- fused attention ----------------
// grid 2048 linear, XCD-swizzled. S^T = K*Q^T via 16x16x32 (C-layout == A-frag
// of 16x16x16), exp in-register, PV via 16x16x16. Vs rows padded to 40 halves.
__global__ __launch_bounds__(256, 4)
void attn_kernel(const _Float16* __restrict__ Qt, const _Float16* __restrict__ K,
                 const _Float16* __restrict__ Vt, const unsigned long long* __restrict__ mbits,
                 float* __restrict__ out) {
  __shared__ _Float16 Ks[2 * 64 * 32];  // [ks=d/32][t][32], stage16 target
  __shared__ _Float16 Vs[2 * 64 * 40];  // [tc=t/32][d][40 padded]
  int tid = threadIdx.x;
  int lane = tid & 63, w4 = tid >> 6;
  int la = lane & 15, qd = lane >> 4;
  int linear = blockIdx.x;
  int xlo = linear & 7;
  int tmp = linear >> 3;
  int qt = tmp & 15;
  int hb = (tmp >> 4) * 8 + xlo;
  int h = hb & 15, b = hb >> 4;
  const _Float16* Qp = Qt + ((size_t)(b * 16 + h)) * 64 * 1024;  // [d][s]
  const _Float16* Kp = K + ((size_t)(b * 16 + h)) * 1024 * 64;   // [s][d]
  const _Float16* Vp = Vt + ((size_t)(b * 16 + h)) * 64 * 1024;  // [d][s]
  int q0w = qt * 64 + w4 * 16;
  // Q B-frag (one-time): qf[ks][j] = Q[q=q0w+la][d=ks*32+qd*8+j]
  half8 qf[2];
#pragma unroll
  for (int ks = 0; ks < 2; ks++)
#pragma unroll
    for (int j = 0; j < 8; j++)
      qf[ks][j] = Qp[(size_t)(ks * 32 + qd * 8 + j) * 1024 + q0w + la];
  // mask preload: 4 u64 (32B coalesced) per lane covers all 16 t-tiles
  unsigned long long mq[4];
  {
    const ulonglong2* mp =
        (const ulonglong2*)(mbits + ((size_t)b * 1024 + q0w + la) * 16 + qd * 4);
    ulonglong2 m01 = mp[0];
    ulonglong2 m23 = mp[1];
    mq[0] = m01.x; mq[1] = m01.y; mq[2] = m23.x; mq[3] = m23.y;
  }
  f32x4 acco[4] = {};
  float rs = 0.0f;
  int r = tid >> 2, c = (tid & 3) * 8;  // r: 0..63, c in {0,8,16,24}
  _Float16* kbase = Ks + w4 * 512;
  for (int tt = 0; tt < 16; tt++) {
    // V: VGPR round-trip into padded LDS (global_load_lds can't pad — m104/m108)
    half8 v0 = *(const half8*)(Vp + (size_t)r * 1024 + tt * 64 + c);
    half8 v1 = *(const half8*)(Vp + (size_t)r * 1024 + tt * 64 + 32 + c);
    // K: async stage16 (unpadded layout is conflict-free for b128 reads)
    stage16(Kp + (size_t)(tt * 64 + r) * 64 + c, kbase, lane);
    stage16(Kp + (size_t)(tt * 64 + r) * 64 + 32 + c, kbase + 2048, lane);
    *(half8*)(Vs + r * 40 + c) = v0;         // tc=0 (t32 = c..c+7)
    *(half8*)(Vs + 2560 + r * 40 + c) = v1;  // tc=1
    __syncthreads();
    // S^T tiles: D[t' = qd*4+rg][q = la], A = K-frag, B = Q-frag
    f32x4 accs[4] = {};
#pragma unroll
    for (int tsub = 0; tsub < 4; tsub++)
#pragma unroll
      for (int ks = 0; ks < 2; ks++) {
        half8 kf = *(const half8*)(Ks + ks * 2048 + (tsub * 16 + la) * 32 + qd * 8);
        accs[tsub] = __builtin_amdgcn_mfma_f32_16x16x32_f16(kf, qf[ks], accs[tsub], 0, 0, 0);
      }
    unsigned long long mw = __shfl(mq[tt & 3], ((tt >> 2) << 4) + la);
#pragma unroll
    for (int tsub = 0; tsub < 4; tsub++) {
      half4 pf;
#pragma unroll
      for (int rg = 0; rg < 4; rg++) {
        float e = ((mw >> (tsub * 16 + qd * 4 + rg)) & 1ull) ? __expf(accs[tsub][rg]) : 0.0f;
        rs += e;
        pf[rg] = (_Float16)e;
      }
#pragma unroll
      for (int nsub = 0; nsub < 4; nsub++) {
        half4 vf = *(const half4*)(Vs + (tsub >> 1) * 2560 + (nsub * 16 + la) * 40 +
                                   (tsub & 1) * 16 + qd * 4);
        acco[nsub] = __builtin_amdgcn_mfma_f32_16x16x16f16(pf, vf, acco[nsub], 0, 0, 0);
      }
    }
    __syncthreads();
  }
  rs += __shfl_xor(rs, 16);
  rs += __shfl_xor(rs, 32);
  float inv_q = 1.0f / (rs + 1e-8f);
  float* op = out + (size_t)b * 1024 * 1024 + (size_t)h * 64;
#pragma unroll
  for (int rg = 0; rg < 4; rg++) {
    float inv = __shfl(inv_q, qd * 4 + rg);
    int s = q0w + qd * 4 + rg;
#pragma unroll
    for (int nsub = 0; nsub < 4; nsub++)
      op[(size_t)s * 1024 + nsub * 16 + la] = acco[nsub][rg] * inv;
  }
}

extern "C" void kernel_launch(void* const* d_in, const int* in_sizes, int n_in,
                              void* d_out, int out_size, void* d_ws, size_t ws_size,
                              hipStream_t stream) {
  (void)in_sizes; (void)n_in; (void)out_size; (void)ws_size;
  const float* x = (const float*)d_in[0];
  const float* am = (const float*)d_in[1];
  const float* Wq = (const float*)d_in[2];
  const float* Wk = (const float*)d_in[3];
  const float* Wv = (const float*)d_in[4];
  float* out = (float*)d_out;

  char* p = (char*)d_ws;
  _Float16* xb = (_Float16*)p;    p += (size_t)8192 * 1024 * 2;
  _Float16* Wqkvt = (_Float16*)p; p += (size_t)3 * 1024 * 1024 * 2;
  _Float16* Qt = (_Float16*)p;    p += (size_t)8192 * 1024 * 2;   // [b,h,d,s]
  _Float16* Kh = (_Float16*)p;    p += (size_t)8192 * 1024 * 2;   // [b,h,s,d]
  _Float16* Vth = (_Float16*)p;   p += (size_t)8192 * 1024 * 2;   // [b,h,d,s]
  unsigned long long* mb = (unsigned long long*)p;

  cast_x_kernel<<<8192, 256, 0, stream>>>(x, xb);
  wtrans_kernel<<<dim3(32, 32, 3), 256, 0, stream>>>(Wq, Wk, Wv, Wqkvt);
  maskbits_kernel<<<32768, 256, 0, stream>>>(am, mb);
  gemm_kernel<<<dim3(24, 64), 256, 0, stream>>>(xb, Wqkvt, Qt, Kh, Vth);
  attn_kernel<<<2048, 256, 0, stream>>>(Qt, Kh, Vth, mb, out);
}